// Round 11
// baseline (6083.312 us; speedup 1.0000x reference)
//
#include <hip/hip_runtime.h>
#include <stdint.h>

#define T_STEPS 101
#define ROWS 1600
#define NTHR 320            /* 5 waves; 1600/320 = exactly 5 row-slots/thread */
#define NBLK 512            /* 2 batches per block, 1024 batches total */
#define NZ1 40
#define NZ2 50
#define OFF2 (NZ1 * ROWS)              /* 64000  */
#define OFF3 (OFF2 + NZ2 * ROWS)       /* 144000 */
#define NZTOT (OFF3 + NZ2 * ROWS)      /* 224000 entries */

/* ws byte offsets */
#define ENT_OFF 0
#define BB_OFF  (NZTOT * 8)            /* float2 {beta, bias} [3][1600] */
#define SA_OFF  (BB_OFF + 3 * ROWS * 8) /* float sigmoid(tau_m) [3][200] */

__device__ __forceinline__ float sigmoidf(float v) { return 1.0f / (1.0f + expf(-v)); }

// ---------------------------------------------------------------------------
// Prep: fused CSR entries {w_bits, byte_off} (SoA [j][1600], ascending col =
// round-1's verified op order; padding {0,0} is exact). byte_off scale: L1=8
// (float2 k1 table), L2/3=2 (u16 spike table). Also precompute per-row
// {sigmoid(tau_n), bias} float2 and per-neuron sigmoid(tau_m).
// ---------------------------------------------------------------------------
__global__ void prep_kernel(const float* __restrict__ W1, const float* __restrict__ W2,
                            const float* __restrict__ W3,
                            const float* __restrict__ b1, const float* __restrict__ tn1,
                            const float* __restrict__ tm1,
                            const float* __restrict__ b2, const float* __restrict__ tn2,
                            const float* __restrict__ tm2,
                            const float* __restrict__ b3, const float* __restrict__ tn3,
                            const float* __restrict__ tm3,
                            uint8_t* __restrict__ ws) {
  int gid = blockIdx.x * blockDim.x + threadIdx.x;
  if (gid >= 3 * ROWS) return;
  int l = gid / ROWS, r = gid - l * ROWS;
  const float *W, *bb, *tn, *tm; int in_f, knz, off, scale;
  if (l == 0)      { W = W1; bb = b1; tn = tn1; tm = tm1; in_f = 320; knz = NZ1; off = 0;    scale = 8; }
  else if (l == 1) { W = W2; bb = b2; tn = tn2; tm = tm2; in_f = 400; knz = NZ2; off = OFF2; scale = 2; }
  else             { W = W3; bb = b3; tn = tn3; tm = tm3; in_f = 400; knz = NZ2; off = OFF3; scale = 2; }
  uint2* e = (uint2*)(ws + ENT_OFF) + off;
  int cnt = 0;
  for (int col = 0; col < in_f; ++col) {
    float w = W[(size_t)r * in_f + col];
    if (w != 0.0f && cnt < knz) {
      e[cnt * ROWS + r] = make_uint2(__float_as_uint(w), (uint32_t)(col * scale));
      ++cnt;
    }
  }
  for (; cnt < knz; ++cnt) e[cnt * ROWS + r] = make_uint2(0u, 0u);
  ((float2*)(ws + BB_OFF))[l * ROWS + r] = make_float2(sigmoidf(tn[r]), bb[r]);
  if (r < 200) ((float*)(ws + SA_OFF))[l * 200 + r] = sigmoidf(tm[r]);
}

// ---------------------------------------------------------------------------
// One row-slot, 2 batch lanes. Fused gather (1 dwordx2 + 1 LDS read + 2 fma
// per nz), round-9's exact math forms/order. Constants from LDS.
// ---------------------------------------------------------------------------
template<int KNZ, bool F32>
__device__ __forceinline__ void slot_compute(
    int tid, int r, const uint2* __restrict__ ent, const uint8_t* __restrict__ ktab,
    const float2* __restrict__ bbL, const float* __restrict__ saL,
    float (&dreg)[2], uint8_t (*s_l)[2], float (*mem_l)[2])
{
  const float2 bb = bbL[r];
  const float bt = bb.x;
  float a0 = bb.y, a1 = bb.y;
  const uint2* ep = ent + r;
#pragma unroll 10
  for (int j = 0; j < KNZ; ++j) {
    const uint2 e = ep[(size_t)j * ROWS];
    const float w = __uint_as_float(e.x);
    if constexpr (F32) {
      const float2 kv = *reinterpret_cast<const float2*>(ktab + e.y);
      a0 = fmaf(w, kv.x, a0);
      a1 = fmaf(w, kv.y, a1);
    } else {
      const uint32_t q = *reinterpret_cast<const uint16_t*>(ktab + e.y);
      a0 = fmaf(w, (float)(q & 0xffu), a0);
      a1 = fmaf(w, (float)(q >> 8), a1);
    }
  }
  const float ob = 1.0f - bt;
  float d0 = fmaf(bt, dreg[0], ob * a0);
  float d1 = fmaf(bt, dreg[1], ob * a1);
  dreg[0] = d0; dreg[1] = d1;
  d0 += __shfl_xor(d0, 1); d0 += __shfl_xor(d0, 2); d0 += __shfl_xor(d0, 4);
  d1 += __shfl_xor(d1, 1); d1 += __shfl_xor(d1, 2); d1 += __shfl_xor(d1, 4);
  if ((tid & 7) == 0) {
    const int n = r >> 3;
    const float al = saL[n], oa = 1.0f - al;
    float2 mv = *reinterpret_cast<float2*>(&mem_l[n][0]);
    const uint32_t so = *reinterpret_cast<uint16_t*>(&s_l[n][0]);
    const float m0 = fmaf(mv.x - (float)(so & 0xffu), al, oa * d0);
    const float m1 = fmaf(mv.y - (float)(so >> 8),    al, oa * d1);
    *reinterpret_cast<float2*>(&mem_l[n][0]) = make_float2(m0, m1);
    const uint16_t sn = (uint16_t)((m0 > 1.0f ? 1u : 0u) | (m1 > 1.0f ? 0x100u : 0u));
    *reinterpret_cast<uint16_t*>(&s_l[n][0]) = sn;
  }
}

// ---------------------------------------------------------------------------
// Main kernel: 512 blocks x 320 threads (5 waves), 2 batches/block.
// 1600 rows / 320 threads = exactly 5 slots/thread: zero wave imbalance
// (round 9/10's 8-wave layout had a 4-vs-3-slot critical wave = 78% eff).
// Constants in LDS (not registers) keep VGPRs low for co-residency.
// ---------------------------------------------------------------------------
__global__ void __launch_bounds__(NTHR, 2)
snn_main(const float* __restrict__ x,
         const float* __restrict__ W4, const float* __restrict__ b4,
         const float* __restrict__ tm4,
         const uint2* __restrict__ ent,
         const float2* __restrict__ bbG, const float* __restrict__ saG,
         float* __restrict__ out)
{
  __shared__ __align__(16) float2   k1f[320];          // L1 table: x | s1 (f32 pairs)
  __shared__ __align__(4)  uint16_t k23u[400];         // L2/3 table: spike u16 pairs
  __shared__ __align__(4)  uint8_t  s_lds[3][200][2];
  __shared__ __align__(16) float    mem_lds[3][200][2];
  __shared__ float  w4_lds[12][201];
  __shared__ float2 bbL[3 * ROWS];                     // {beta, bias} per row
  __shared__ float  saL[3 * 200];                      // alpha per neuron

  const int tid = threadIdx.x;
  const int bg  = blockIdx.x;          // batches bg*2, bg*2+1

  for (int idx = tid; idx < 300; idx += NTHR) {
    reinterpret_cast<uint32_t*>(&s_lds[0][0][0])[idx] = 0u;
    reinterpret_cast<float4*>(&mem_lds[0][0][0])[idx] = make_float4(0.f, 0.f, 0.f, 0.f);
  }
  for (int idx = tid; idx < 12 * 200; idx += NTHR)
    w4_lds[idx / 200][idx % 200] = W4[idx];
  for (int idx = tid; idx < 3 * ROWS; idx += NTHR) bbL[idx] = bbG[idx];
  for (int idx = tid; idx < 3 * 200; idx += NTHR) saL[idx] = saG[idx];

  float d[3][5][2];
#pragma unroll
  for (int l = 0; l < 3; ++l)
#pragma unroll
    for (int i = 0; i < 5; ++i)
#pragma unroll
      for (int b = 0; b < 2; ++b) d[l][i][b] = 0.0f;

  float m4_reg = 0.0f, m4_acc = 0.0f, a4 = 0.0f, b4r = 0.0f;
  if (tid < 96) { const int o = tid >> 3; a4 = sigmoidf(tm4[o]); b4r = b4[o]; }
  __syncthreads();

  const uint8_t* k1b = reinterpret_cast<const uint8_t*>(&k1f[0]);
  const uint8_t* k2b = reinterpret_cast<const uint8_t*>(&k23u[0]);

  for (int t = 0; t < T_STEPS; ++t) {
    // ---- stage k1 = [x_t | s1(old)] on tid>=96 (overlaps prev readout) --
    if (tid >= 96) {
      for (int e = tid - 96; e < 240; e += 224) {
        const int bat = e / 120, cf = e - bat * 120;
        const int c = cf / 40, f = cf - c * 40;
        reinterpret_cast<float*>(&k1f[cf])[bat] =
            x[(((size_t)(bg * 2 + bat) * 3 + c) * T_STEPS + t) * 40 + f];
      }
      if (tid < 296) {
        const int n = tid - 96;
        const uint32_t so = *reinterpret_cast<const uint16_t*>(&s_lds[0][n][0]);
        k1f[120 + n] = make_float2((float)(so & 0xffu), (float)(so >> 8));
      }
    }
    __syncthreads();
    // ---- L1: 5 slots, all waves equally loaded -------------------------
    slot_compute<NZ1, true>(tid, tid,        ent, k1b, bbL,        saL,       d[0][0], s_lds[0], mem_lds[0]);
    slot_compute<NZ1, true>(tid, tid + 320,  ent, k1b, bbL,        saL,       d[0][1], s_lds[0], mem_lds[0]);
    slot_compute<NZ1, true>(tid, tid + 640,  ent, k1b, bbL,        saL,       d[0][2], s_lds[0], mem_lds[0]);
    slot_compute<NZ1, true>(tid, tid + 960,  ent, k1b, bbL,        saL,       d[0][3], s_lds[0], mem_lds[0]);
    slot_compute<NZ1, true>(tid, tid + 1280, ent, k1b, bbL,        saL,       d[0][4], s_lds[0], mem_lds[0]);
    __syncthreads();
    // ---- stage k2 = [s1(new) | s2(old)] as u16 -------------------------
    for (int i = tid; i < 400; i += NTHR)
      k23u[i] = (i < 200) ? *reinterpret_cast<const uint16_t*>(&s_lds[0][i][0])
                          : *reinterpret_cast<const uint16_t*>(&s_lds[1][i - 200][0]);
    __syncthreads();
    slot_compute<NZ2, false>(tid, tid,        ent + OFF2, k2b, bbL + ROWS, saL + 200, d[1][0], s_lds[1], mem_lds[1]);
    slot_compute<NZ2, false>(tid, tid + 320,  ent + OFF2, k2b, bbL + ROWS, saL + 200, d[1][1], s_lds[1], mem_lds[1]);
    slot_compute<NZ2, false>(tid, tid + 640,  ent + OFF2, k2b, bbL + ROWS, saL + 200, d[1][2], s_lds[1], mem_lds[1]);
    slot_compute<NZ2, false>(tid, tid + 960,  ent + OFF2, k2b, bbL + ROWS, saL + 200, d[1][3], s_lds[1], mem_lds[1]);
    slot_compute<NZ2, false>(tid, tid + 1280, ent + OFF2, k2b, bbL + ROWS, saL + 200, d[1][4], s_lds[1], mem_lds[1]);
    __syncthreads();
    // ---- stage k3 = [s2(new) | s3(old)] as u16 -------------------------
    for (int i = tid; i < 400; i += NTHR)
      k23u[i] = (i < 200) ? *reinterpret_cast<const uint16_t*>(&s_lds[1][i][0])
                          : *reinterpret_cast<const uint16_t*>(&s_lds[2][i - 200][0]);
    __syncthreads();
    slot_compute<NZ2, false>(tid, tid,        ent + OFF3, k2b, bbL + 2 * ROWS, saL + 400, d[2][0], s_lds[2], mem_lds[2]);
    slot_compute<NZ2, false>(tid, tid + 320,  ent + OFF3, k2b, bbL + 2 * ROWS, saL + 400, d[2][1], s_lds[2], mem_lds[2]);
    slot_compute<NZ2, false>(tid, tid + 640,  ent + OFF3, k2b, bbL + 2 * ROWS, saL + 400, d[2][2], s_lds[2], mem_lds[2]);
    slot_compute<NZ2, false>(tid, tid + 960,  ent + OFF3, k2b, bbL + 2 * ROWS, saL + 400, d[2][3], s_lds[2], mem_lds[2]);
    slot_compute<NZ2, false>(tid, tid + 1280, ent + OFF3, k2b, bbL + 2 * ROWS, saL + 400, d[2][4], s_lds[2], mem_lds[2]);
    __syncthreads();
    // ---- leaky readout: 96 threads, 4 lanes per (o,bat) ----------------
    // (overlaps next step's k1 staging on tid>=96; reassociated sum is
    //  fine -- no threshold decision downstream of the readout)
    if (tid < 96) {
      const int sub = tid & 3, pair = tid >> 2, o = pair >> 1, bat = pair & 1;
      float part = 0.0f;
#pragma unroll 10
      for (int m = 0; m < 50; ++m) {
        const int n = 4 * m + sub;
        part = fmaf(w4_lds[o][n], (float)s_lds[2][n][bat], part);
      }
      part += __shfl_xor(part, 1);
      part += __shfl_xor(part, 2);
      const float dot = b4r + part;
      m4_reg = a4 * m4_reg + (1.0f - a4) * dot;
      m4_acc += m4_reg;
    }
  }

  // ---- log_softmax(acc / T) -------------------------------------------
  __syncthreads();
  if (tid < 96 && (tid & 3) == 0) {
    const int pair = tid >> 2, o = pair >> 1, bat = pair & 1;
    reinterpret_cast<float*>(&k1f[o])[bat] = m4_acc * (1.0f / (float)T_STEPS);
  }
  __syncthreads();
  if (tid < 2) {
    const int bat = tid;
    float v[12], mx = -1e30f;
#pragma unroll
    for (int o = 0; o < 12; ++o) {
      v[o] = reinterpret_cast<float*>(&k1f[o])[bat];
      mx = fmaxf(mx, v[o]);
    }
    float s = 0.0f;
#pragma unroll
    for (int o = 0; o < 12; ++o) s += expf(v[o] - mx);
    const float ls = logf(s);
#pragma unroll
    for (int o = 0; o < 12; ++o)
      out[((size_t)(bg * 2 + bat)) * 12 + o] = v[o] - mx - ls;
  }
}

// ---------------------------------------------------------------------------
extern "C" void kernel_launch(void* const* d_in, const int* in_sizes, int n_in,
                              void* d_out, int out_size, void* d_ws, size_t ws_size,
                              hipStream_t stream) {
  (void)in_sizes; (void)n_in; (void)out_size; (void)ws_size;
  const float* x   = (const float*)d_in[0];
  const float* W1  = (const float*)d_in[1];
  const float* b1  = (const float*)d_in[2];
  const float* tm1 = (const float*)d_in[3];
  const float* tn1 = (const float*)d_in[4];
  const float* W2  = (const float*)d_in[5];
  const float* b2  = (const float*)d_in[6];
  const float* tm2 = (const float*)d_in[7];
  const float* tn2 = (const float*)d_in[8];
  const float* W3  = (const float*)d_in[9];
  const float* b3  = (const float*)d_in[10];
  const float* tm3 = (const float*)d_in[11];
  const float* tn3 = (const float*)d_in[12];
  const float* W4  = (const float*)d_in[13];
  const float* b4  = (const float*)d_in[14];
  const float* tm4 = (const float*)d_in[15];

  uint8_t* ws = (uint8_t*)d_ws;
  const uint2*  ent = (const uint2*)(ws + ENT_OFF);
  const float2* bbG = (const float2*)(ws + BB_OFF);
  const float*  saG = (const float*)(ws + SA_OFF);

  prep_kernel<<<dim3(19), dim3(256), 0, stream>>>(
      W1, W2, W3, b1, tn1, tm1, b2, tn2, tm2, b3, tn3, tm3, ws);
  snn_main<<<dim3(NBLK), dim3(NTHR), 0, stream>>>(
      x, W4, b4, tm4, ent, bbG, saG, (float*)d_out);
}

// Round 12
// 3593.880 us; speedup vs baseline: 1.6927x; 1.6927x over previous
//
#include <hip/hip_runtime.h>
#include <stdint.h>

#define T_STEPS 101
#define ROWS 1600
#define NTHR 512
#define NBLK 512            /* 2 batches per block, 1024 batches total */
#define NP1 20              /* L1: 40 nz = 20 pairs */
#define NP23 25             /* L2/3: 50 nz = 25 pairs */
#define PO2 (NP1 * ROWS)               /* 32000 pairs */
#define PO3 (PO2 + NP23 * ROWS)        /* 72000 */
#define NPTOT (PO3 + NP23 * ROWS)      /* 112000 pairs */

/* ws byte offsets */
#define W2_OFF 0
#define C2_OFF (NPTOT * 8)                   /* 896000  */
#define BB_OFF (C2_OFF + NPTOT * 4)          /* 1344000 */
#define SA_OFF (BB_OFF + 3 * ROWS * 8)       /* 1382400 */

__device__ __forceinline__ float sigmoidf(float v) { return 1.0f / (1.0f + expf(-v)); }

// ---------------------------------------------------------------------------
// Prep: paired CSR streams. w2[p][1600] float2 = weights (2j, 2j+1);
// c2[p][1600] u32 = two u16 byte-offsets. Ascending col order (round-1's
// verified op order); padding w=0/c=0 is exact (fmaf(0,k[0],a)==a).
// Offset scale: L1 col*8 (float2 k1 table), L2/3 col*2 (u16 spike table).
// Also {sigmoid(tau_n), bias} float2 per row and sigmoid(tau_m) per neuron.
// ---------------------------------------------------------------------------
__global__ void prep_kernel(const float* __restrict__ W1, const float* __restrict__ W2,
                            const float* __restrict__ W3,
                            const float* __restrict__ b1, const float* __restrict__ tn1,
                            const float* __restrict__ tm1,
                            const float* __restrict__ b2, const float* __restrict__ tn2,
                            const float* __restrict__ tm2,
                            const float* __restrict__ b3, const float* __restrict__ tn3,
                            const float* __restrict__ tm3,
                            uint8_t* __restrict__ ws) {
  int gid = blockIdx.x * blockDim.x + threadIdx.x;
  if (gid >= 3 * ROWS) return;
  int l = gid / ROWS, r = gid - l * ROWS;
  const float *W, *bb, *tn, *tm; int in_f, knz, np, poff, scale;
  if (l == 0)      { W = W1; bb = b1; tn = tn1; tm = tm1; in_f = 320; knz = 40; np = NP1;  poff = 0;   scale = 8; }
  else if (l == 1) { W = W2; bb = b2; tn = tn2; tm = tm2; in_f = 400; knz = 50; np = NP23; poff = PO2; scale = 2; }
  else             { W = W3; bb = b3; tn = tn3; tm = tm3; in_f = 400; knz = 50; np = NP23; poff = PO3; scale = 2; }
  float2* w2 = (float2*)(ws + W2_OFF) + poff;
  uint32_t* c2 = (uint32_t*)(ws + C2_OFF) + poff;
  float wl[52]; uint32_t cl[52];
  int cnt = 0;
  for (int col = 0; col < in_f; ++col) {
    float w = W[(size_t)r * in_f + col];
    if (w != 0.0f && cnt < knz) { wl[cnt] = w; cl[cnt] = (uint32_t)(col * scale); ++cnt; }
  }
  for (; cnt < 2 * np; ++cnt) { wl[cnt] = 0.0f; cl[cnt] = 0u; }
  for (int p = 0; p < np; ++p) {
    w2[p * ROWS + r] = make_float2(wl[2 * p], wl[2 * p + 1]);
    c2[p * ROWS + r] = cl[2 * p] | (cl[2 * p + 1] << 16);
  }
  ((float2*)(ws + BB_OFF))[l * ROWS + r] = make_float2(sigmoidf(tn[r]), bb[r]);
  if (r < 200) ((float*)(ws + SA_OFF))[l * 200 + r] = sigmoidf(tm[r]);
}

// ---------------------------------------------------------------------------
// One row-slot, 2 batch lanes, paired gather: per 2 nz = 1 dwordx2 (w pair)
// + 1 dword (2 cols) + 2 LDS reads + 4 fma. Ascending j order == verified
// round-9 chain. Constants from LDS (keeps VGPRs under the 64-reg
// co-residency cliff).
// ---------------------------------------------------------------------------
template<int NP, bool F32>
__device__ __forceinline__ void slot_compute(
    int tid, int r,
    const float2* __restrict__ w2, const uint32_t* __restrict__ c2,
    const uint8_t* __restrict__ ktab,
    const float2* __restrict__ bbL, const float* __restrict__ saL,
    float (&dreg)[2], uint8_t (*s_l)[2], float (*mem_l)[2])
{
  const float2 bb = bbL[r];
  const float bt = bb.x;
  float a0 = bb.y, a1 = bb.y;
  const float2* wp = w2 + r;
  const uint32_t* cp = c2 + r;
#pragma unroll 5
  for (int p = 0; p < NP; ++p) {
    const float2 w = wp[(size_t)p * ROWS];
    const uint32_t c = cp[(size_t)p * ROWS];
    if constexpr (F32) {
      { const float2 kv = *reinterpret_cast<const float2*>(ktab + (c & 0xffffu));
        a0 = fmaf(w.x, kv.x, a0); a1 = fmaf(w.x, kv.y, a1); }
      { const float2 kv = *reinterpret_cast<const float2*>(ktab + (c >> 16));
        a0 = fmaf(w.y, kv.x, a0); a1 = fmaf(w.y, kv.y, a1); }
    } else {
      { const uint32_t q = *reinterpret_cast<const uint16_t*>(ktab + (c & 0xffffu));
        a0 = fmaf(w.x, (float)(q & 0xffu), a0); a1 = fmaf(w.x, (float)(q >> 8), a1); }
      { const uint32_t q = *reinterpret_cast<const uint16_t*>(ktab + (c >> 16));
        a0 = fmaf(w.y, (float)(q & 0xffu), a0); a1 = fmaf(w.y, (float)(q >> 8), a1); }
    }
  }
  const float ob = 1.0f - bt;
  float d0 = fmaf(bt, dreg[0], ob * a0);
  float d1 = fmaf(bt, dreg[1], ob * a1);
  dreg[0] = d0; dreg[1] = d1;
  d0 += __shfl_xor(d0, 1); d0 += __shfl_xor(d0, 2); d0 += __shfl_xor(d0, 4);
  d1 += __shfl_xor(d1, 1); d1 += __shfl_xor(d1, 2); d1 += __shfl_xor(d1, 4);
  if ((tid & 7) == 0) {
    const int n = r >> 3;
    const float al = saL[n], oa = 1.0f - al;
    float2 mv = *reinterpret_cast<float2*>(&mem_l[n][0]);
    const uint32_t so = *reinterpret_cast<uint16_t*>(&s_l[n][0]);
    const float m0 = fmaf(mv.x - (float)(so & 0xffu), al, oa * d0);
    const float m1 = fmaf(mv.y - (float)(so >> 8),    al, oa * d1);
    *reinterpret_cast<float2*>(&mem_l[n][0]) = make_float2(m0, m1);
    const uint16_t sn = (uint16_t)((m0 > 1.0f ? 1u : 0u) | (m1 > 1.0f ? 0x100u : 0u));
    *reinterpret_cast<uint16_t*>(&s_l[n][0]) = sn;
  }
}

// ---------------------------------------------------------------------------
// Main kernel: 512 blocks x 512 threads, 2 batches/block (round-9 dataflow).
// __launch_bounds__(512, 4) caps VGPRs at 64 = the measured co-residency
// cliff (r7: VGPR 64 -> 16 waves/CU; r9: VGPR 112 -> 8 waves). Constants
// live in LDS (r11-verified) so the ~55-60 reg live set fits the cap.
// ---------------------------------------------------------------------------
__global__ void __launch_bounds__(NTHR, 4)
snn_main(const float* __restrict__ x,
         const float* __restrict__ W4, const float* __restrict__ b4,
         const float* __restrict__ tm4,
         const float2* __restrict__ w2G, const uint32_t* __restrict__ c2G,
         const float2* __restrict__ bbG, const float* __restrict__ saG,
         float* __restrict__ out)
{
  __shared__ __align__(16) float2   k1f[320];          // L1 table: x | s1 (f32 pairs)
  __shared__ __align__(4)  uint8_t  k23[400][2];       // L2/3 table: spike u8 pairs
  __shared__ __align__(4)  uint8_t  s_lds[3][200][2];
  __shared__ __align__(16) float    mem_lds[3][200][2];
  __shared__ float  w4_lds[12][201];
  __shared__ float2 bbL[3 * ROWS];
  __shared__ float  saL[3 * 200];

  const int tid = threadIdx.x;
  const int bg  = blockIdx.x;          // batches bg*2, bg*2+1

  for (int idx = tid; idx < 300; idx += NTHR) {
    reinterpret_cast<uint32_t*>(&s_lds[0][0][0])[idx] = 0u;
    reinterpret_cast<float4*>(&mem_lds[0][0][0])[idx] = make_float4(0.f, 0.f, 0.f, 0.f);
  }
  for (int idx = tid; idx < 12 * 200; idx += NTHR)
    w4_lds[idx / 200][idx % 200] = W4[idx];
  for (int idx = tid; idx < 3 * ROWS; idx += NTHR) bbL[idx] = bbG[idx];
  for (int idx = tid; idx < 3 * 200; idx += NTHR) saL[idx] = saG[idx];

  float d[3][4][2];
#pragma unroll
  for (int l = 0; l < 3; ++l)
#pragma unroll
    for (int i = 0; i < 4; ++i)
#pragma unroll
      for (int b = 0; b < 2; ++b) d[l][i][b] = 0.0f;

  float m4_reg = 0.0f, m4_acc = 0.0f, a4 = 0.0f, b4r = 0.0f;
  if (tid < 96) { const int o = tid >> 3; a4 = sigmoidf(tm4[o]); b4r = b4[o]; }
  __syncthreads();

  const uint8_t* k1b = reinterpret_cast<const uint8_t*>(&k1f[0]);
  const uint8_t* k2b = reinterpret_cast<const uint8_t*>(&k23[0][0]);

  for (int t = 0; t < T_STEPS; ++t) {
    // ---- build k1 = [x_t | s1(old)] -----------------------------------
    if (tid < 240) {
      const int bat = tid / 120, cf = tid - bat * 120;
      const int c = cf / 40, f = cf - c * 40;
      reinterpret_cast<float*>(&k1f[cf])[bat] =
          x[(((size_t)(bg * 2 + bat) * 3 + c) * T_STEPS + t) * 40 + f];
    }
    if (tid < 200) {
      const uint32_t so = *reinterpret_cast<const uint16_t*>(&s_lds[0][tid][0]);
      k1f[120 + tid] = make_float2((float)(so & 0xffu), (float)(so >> 8));
    }
    __syncthreads();
    slot_compute<NP1, true>(tid, tid,        w2G, c2G, k1b, bbL, saL, d[0][0], s_lds[0], mem_lds[0]);
    slot_compute<NP1, true>(tid, tid + 512,  w2G, c2G, k1b, bbL, saL, d[0][1], s_lds[0], mem_lds[0]);
    slot_compute<NP1, true>(tid, tid + 1024, w2G, c2G, k1b, bbL, saL, d[0][2], s_lds[0], mem_lds[0]);
    if (tid < 64)
      slot_compute<NP1, true>(tid, 1536 + tid, w2G, c2G, k1b, bbL, saL, d[0][3], s_lds[0], mem_lds[0]);
    __syncthreads();
    // ---- build k2 = [s1(new) | s2(old)] (u32 copies) ------------------
    if (tid < 100)
      reinterpret_cast<uint32_t*>(&k23[0][0])[tid] =
          reinterpret_cast<const uint32_t*>(&s_lds[0][0][0])[tid];
    else if (tid < 200)
      reinterpret_cast<uint32_t*>(&k23[0][0])[tid] =
          reinterpret_cast<const uint32_t*>(&s_lds[1][0][0])[tid - 100];
    __syncthreads();
    slot_compute<NP23, false>(tid, tid,        w2G + PO2, c2G + PO2, k2b, bbL + ROWS, saL + 200, d[1][0], s_lds[1], mem_lds[1]);
    slot_compute<NP23, false>(tid, tid + 512,  w2G + PO2, c2G + PO2, k2b, bbL + ROWS, saL + 200, d[1][1], s_lds[1], mem_lds[1]);
    slot_compute<NP23, false>(tid, tid + 1024, w2G + PO2, c2G + PO2, k2b, bbL + ROWS, saL + 200, d[1][2], s_lds[1], mem_lds[1]);
    if (tid < 64)
      slot_compute<NP23, false>(tid, 1536 + tid, w2G + PO2, c2G + PO2, k2b, bbL + ROWS, saL + 200, d[1][3], s_lds[1], mem_lds[1]);
    __syncthreads();
    // ---- build k3 = [s2(new) | s3(old)] -------------------------------
    if (tid < 100)
      reinterpret_cast<uint32_t*>(&k23[0][0])[tid] =
          reinterpret_cast<const uint32_t*>(&s_lds[1][0][0])[tid];
    else if (tid < 200)
      reinterpret_cast<uint32_t*>(&k23[0][0])[tid] =
          reinterpret_cast<const uint32_t*>(&s_lds[2][0][0])[tid - 100];
    __syncthreads();
    slot_compute<NP23, false>(tid, tid,        w2G + PO3, c2G + PO3, k2b, bbL + 2 * ROWS, saL + 400, d[2][0], s_lds[2], mem_lds[2]);
    slot_compute<NP23, false>(tid, tid + 512,  w2G + PO3, c2G + PO3, k2b, bbL + 2 * ROWS, saL + 400, d[2][1], s_lds[2], mem_lds[2]);
    slot_compute<NP23, false>(tid, tid + 1024, w2G + PO3, c2G + PO3, k2b, bbL + 2 * ROWS, saL + 400, d[2][2], s_lds[2], mem_lds[2]);
    if (tid < 64)
      slot_compute<NP23, false>(tid, 1536 + tid, w2G + PO3, c2G + PO3, k2b, bbL + 2 * ROWS, saL + 400, d[2][3], s_lds[2], mem_lds[2]);
    __syncthreads();
    // ---- leaky readout: 96 threads, 4 lanes per (o,bat) ----------------
    // (reassociated partial sums -- verified absmax 0.0 in round 11)
    if (tid < 96) {
      const int sub = tid & 3, pair = tid >> 2, o = pair >> 1, bat = pair & 1;
      float part = 0.0f;
#pragma unroll 10
      for (int m = 0; m < 50; ++m) {
        const int n = 4 * m + sub;
        part = fmaf(w4_lds[o][n], (float)s_lds[2][n][bat], part);
      }
      part += __shfl_xor(part, 1);
      part += __shfl_xor(part, 2);
      const float dot = b4r + part;
      m4_reg = a4 * m4_reg + (1.0f - a4) * dot;
      m4_acc += m4_reg;
    }
    // no trailing barrier: stage-k1(t+1) touches only k1f / s_lds[0];
    // readout touches only s_lds[2] / w4_lds.
  }

  // ---- log_softmax(acc / T) -------------------------------------------
  __syncthreads();
  if (tid < 96 && (tid & 3) == 0) {
    const int pair = tid >> 2, o = pair >> 1, bat = pair & 1;
    reinterpret_cast<float*>(&k1f[o])[bat] = m4_acc * (1.0f / (float)T_STEPS);
  }
  __syncthreads();
  if (tid < 2) {
    const int bat = tid;
    float v[12], mx = -1e30f;
#pragma unroll
    for (int o = 0; o < 12; ++o) {
      v[o] = reinterpret_cast<float*>(&k1f[o])[bat];
      mx = fmaxf(mx, v[o]);
    }
    float s = 0.0f;
#pragma unroll
    for (int o = 0; o < 12; ++o) s += expf(v[o] - mx);
    const float ls = logf(s);
#pragma unroll
    for (int o = 0; o < 12; ++o)
      out[((size_t)(bg * 2 + bat)) * 12 + o] = v[o] - mx - ls;
  }
}

// ---------------------------------------------------------------------------
extern "C" void kernel_launch(void* const* d_in, const int* in_sizes, int n_in,
                              void* d_out, int out_size, void* d_ws, size_t ws_size,
                              hipStream_t stream) {
  (void)in_sizes; (void)n_in; (void)out_size; (void)ws_size;
  const float* x   = (const float*)d_in[0];
  const float* W1  = (const float*)d_in[1];
  const float* b1  = (const float*)d_in[2];
  const float* tm1 = (const float*)d_in[3];
  const float* tn1 = (const float*)d_in[4];
  const float* W2  = (const float*)d_in[5];
  const float* b2  = (const float*)d_in[6];
  const float* tm2 = (const float*)d_in[7];
  const float* tn2 = (const float*)d_in[8];
  const float* W3  = (const float*)d_in[9];
  const float* b3  = (const float*)d_in[10];
  const float* tm3 = (const float*)d_in[11];
  const float* tn3 = (const float*)d_in[12];
  const float* W4  = (const float*)d_in[13];
  const float* b4  = (const float*)d_in[14];
  const float* tm4 = (const float*)d_in[15];

  uint8_t* ws = (uint8_t*)d_ws;
  const float2*   w2G = (const float2*)(ws + W2_OFF);
  const uint32_t* c2G = (const uint32_t*)(ws + C2_OFF);
  const float2*   bbG = (const float2*)(ws + BB_OFF);
  const float*    saG = (const float*)(ws + SA_OFF);

  prep_kernel<<<dim3(19), dim3(256), 0, stream>>>(
      W1, W2, W3, b1, tn1, tm1, b2, tn2, tm2, b3, tn3, tm3, ws);
  snn_main<<<dim3(NBLK), dim3(NTHR), 0, stream>>>(
      x, W4, b4, tm4, w2G, c2G, bbG, saG, (float*)d_out);
}

// Round 13
// 3188.283 us; speedup vs baseline: 1.9080x; 1.1272x over previous
//
#include <hip/hip_runtime.h>
#include <stdint.h>

#define T_STEPS 101
#define ROWS 1600
#define NTHR 1024
#define NBLK 256            /* 4 batches per block, 1024 batches total */
#define NP1 20              /* L1: 40 nz = 20 pairs */
#define NP23 25             /* L2/3: 50 nz = 25 pairs */
#define PO2 (NP1 * ROWS)               /* 32000 pairs */
#define PO3 (PO2 + NP23 * ROWS)        /* 72000 */
#define NPTOT (PO3 + NP23 * ROWS)      /* 112000 pairs */

/* ws byte offsets */
#define W2_OFF 0
#define C2_OFF (NPTOT * 8)                   /* 896000  */
#define BB_OFF (C2_OFF + NPTOT * 4)          /* 1344000 */
#define SA_OFF (BB_OFF + 3 * ROWS * 8)       /* 1382400 */

__device__ __forceinline__ float sigmoidf(float v) { return 1.0f / (1.0f + expf(-v)); }

// ---------------------------------------------------------------------------
// Prep: paired CSR streams. w2[p][1600] float2 = weights (2j, 2j+1);
// c2[p][1600] u32 = two u16 byte-offsets. Ascending col order (round-1's
// verified op order); padding w=0/c=0 is exact (fmaf(0,k[0],a)==a).
// Offset scale: L1 col*16 (float4 k1 table), L2/3 col*4 (u32 spike table).
// Also {sigmoid(tau_n), bias} float2 per row and sigmoid(tau_m) per neuron.
// ---------------------------------------------------------------------------
__global__ void prep_kernel(const float* __restrict__ W1, const float* __restrict__ W2,
                            const float* __restrict__ W3,
                            const float* __restrict__ b1, const float* __restrict__ tn1,
                            const float* __restrict__ tm1,
                            const float* __restrict__ b2, const float* __restrict__ tn2,
                            const float* __restrict__ tm2,
                            const float* __restrict__ b3, const float* __restrict__ tn3,
                            const float* __restrict__ tm3,
                            uint8_t* __restrict__ ws) {
  int gid = blockIdx.x * blockDim.x + threadIdx.x;
  if (gid >= 3 * ROWS) return;
  int l = gid / ROWS, r = gid - l * ROWS;
  const float *W, *bb, *tn, *tm; int in_f, knz, np, poff, scale;
  if (l == 0)      { W = W1; bb = b1; tn = tn1; tm = tm1; in_f = 320; knz = 40; np = NP1;  poff = 0;   scale = 16; }
  else if (l == 1) { W = W2; bb = b2; tn = tn2; tm = tm2; in_f = 400; knz = 50; np = NP23; poff = PO2; scale = 4; }
  else             { W = W3; bb = b3; tn = tn3; tm = tm3; in_f = 400; knz = 50; np = NP23; poff = PO3; scale = 4; }
  float2* w2 = (float2*)(ws + W2_OFF) + poff;
  uint32_t* c2 = (uint32_t*)(ws + C2_OFF) + poff;
  float wl[52]; uint32_t cl[52];
  int cnt = 0;
  for (int col = 0; col < in_f; ++col) {
    float w = W[(size_t)r * in_f + col];
    if (w != 0.0f && cnt < knz) { wl[cnt] = w; cl[cnt] = (uint32_t)(col * scale); ++cnt; }
  }
  for (; cnt < 2 * np; ++cnt) { wl[cnt] = 0.0f; cl[cnt] = 0u; }
  for (int p = 0; p < np; ++p) {
    w2[p * ROWS + r] = make_float2(wl[2 * p], wl[2 * p + 1]);
    c2[p * ROWS + r] = cl[2 * p] | (cl[2 * p + 1] << 16);
  }
  ((float2*)(ws + BB_OFF))[l * ROWS + r] = make_float2(sigmoidf(tn[r]), bb[r]);
  if (r < 200) ((float*)(ws + SA_OFF))[l * 200 + r] = sigmoidf(tm[r]);
}

// ---------------------------------------------------------------------------
// One row-slot, 4 batch lanes, paired gather: per 2 nz = 1 dwordx2 (w pair)
// + 1 dword (2 cols) + 2 LDS reads + 8 fma. Ascending j order == verified
// round-1 chain; leader mem/spike update is round-1's exact 4-lane code.
// ---------------------------------------------------------------------------
template<int NP, bool F32>
__device__ __forceinline__ void slot_compute(
    int tid, int r,
    const float2* __restrict__ w2, const uint32_t* __restrict__ c2,
    const uint8_t* __restrict__ ktab,
    const float2* __restrict__ bbL, const float* __restrict__ saL,
    float (&dreg)[4], uint8_t (*s_l)[4], float (*mem_l)[4])
{
  const float2 bb = bbL[r];
  const float bt = bb.x;
  float a0 = bb.y, a1 = bb.y, a2 = bb.y, a3 = bb.y;
  const float2* wp = w2 + r;
  const uint32_t* cp = c2 + r;
#pragma unroll 5
  for (int p = 0; p < NP; ++p) {
    const float2 w = wp[(size_t)p * ROWS];
    const uint32_t c = cp[(size_t)p * ROWS];
    if constexpr (F32) {
      { const float4 kv = *reinterpret_cast<const float4*>(ktab + (c & 0xffffu));
        a0 = fmaf(w.x, kv.x, a0); a1 = fmaf(w.x, kv.y, a1);
        a2 = fmaf(w.x, kv.z, a2); a3 = fmaf(w.x, kv.w, a3); }
      { const float4 kv = *reinterpret_cast<const float4*>(ktab + (c >> 16));
        a0 = fmaf(w.y, kv.x, a0); a1 = fmaf(w.y, kv.y, a1);
        a2 = fmaf(w.y, kv.z, a2); a3 = fmaf(w.y, kv.w, a3); }
    } else {
      { const uint32_t q = *reinterpret_cast<const uint32_t*>(ktab + (c & 0xffffu));
        a0 = fmaf(w.x, (float)(q & 0xffu), a0);
        a1 = fmaf(w.x, (float)((q >> 8) & 0xffu), a1);
        a2 = fmaf(w.x, (float)((q >> 16) & 0xffu), a2);
        a3 = fmaf(w.x, (float)(q >> 24), a3); }
      { const uint32_t q = *reinterpret_cast<const uint32_t*>(ktab + (c >> 16));
        a0 = fmaf(w.y, (float)(q & 0xffu), a0);
        a1 = fmaf(w.y, (float)((q >> 8) & 0xffu), a1);
        a2 = fmaf(w.y, (float)((q >> 16) & 0xffu), a2);
        a3 = fmaf(w.y, (float)(q >> 24), a3); }
    }
  }
  const float ob = 1.0f - bt;
  float d0 = fmaf(bt, dreg[0], ob * a0);
  float d1 = fmaf(bt, dreg[1], ob * a1);
  float d2 = fmaf(bt, dreg[2], ob * a2);
  float d3 = fmaf(bt, dreg[3], ob * a3);
  dreg[0] = d0; dreg[1] = d1; dreg[2] = d2; dreg[3] = d3;
  d0 += __shfl_xor(d0, 1); d0 += __shfl_xor(d0, 2); d0 += __shfl_xor(d0, 4);
  d1 += __shfl_xor(d1, 1); d1 += __shfl_xor(d1, 2); d1 += __shfl_xor(d1, 4);
  d2 += __shfl_xor(d2, 1); d2 += __shfl_xor(d2, 2); d2 += __shfl_xor(d2, 4);
  d3 += __shfl_xor(d3, 1); d3 += __shfl_xor(d3, 2); d3 += __shfl_xor(d3, 4);
  if ((tid & 7) == 0) {
    const int n = r >> 3;
    const float al = saL[n], oa = 1.0f - al;
    float4 mv = *reinterpret_cast<float4*>(&mem_l[n][0]);
    const uint32_t so = *reinterpret_cast<uint32_t*>(&s_l[n][0]);
    const float m0 = fmaf(mv.x - (float)(so & 0xffu),         al, oa * d0);
    const float m1 = fmaf(mv.y - (float)((so >> 8) & 0xffu),  al, oa * d1);
    const float m2 = fmaf(mv.z - (float)((so >> 16) & 0xffu), al, oa * d2);
    const float m3 = fmaf(mv.w - (float)(so >> 24),           al, oa * d3);
    *reinterpret_cast<float4*>(&mem_l[n][0]) = make_float4(m0, m1, m2, m3);
    const uint32_t sn = (m0 > 1.0f ? 1u : 0u) | (m1 > 1.0f ? 0x100u : 0u)
                      | (m2 > 1.0f ? 0x10000u : 0u) | (m3 > 1.0f ? 0x1000000u : 0u);
    *reinterpret_cast<uint32_t*>(&s_l[n][0]) = sn;
  }
}

// ---------------------------------------------------------------------------
// Main kernel: 256 blocks x 1024 threads (16 waves/CU, one block), 4
// batches/block. Fuses round-12's two co-resident 2-batch blocks: same wave
// count, but ONE weight/address/LDS-read stream now feeds 4 batch-FMAs ->
// L2 bytes, VMEM instrs, LDS instrs all halved per CU; critical wave does
// 2 gather slots (was 4). Live set (d=24 + consts-in-LDS) fits the 64-VGPR
// default cap (round-12-verified diet).
// Slots: slot0 r=tid (rows 0-1023); slot1 r=tid+576 for tid>=448 (waves
// 7-15; rows 1024-1599) -- readout on waves 0-2 overlaps slot-1 work.
// ---------------------------------------------------------------------------
__global__ void __launch_bounds__(NTHR)
snn_main(const float* __restrict__ x,
         const float* __restrict__ W4, const float* __restrict__ b4,
         const float* __restrict__ tm4,
         const float2* __restrict__ w2G, const uint32_t* __restrict__ c2G,
         const float2* __restrict__ bbG, const float* __restrict__ saG,
         float* __restrict__ out)
{
  __shared__ __align__(16) float4   k1f[320];          // L1 table: x | s1 (f32 quads)
  __shared__ __align__(4)  uint8_t  k23[400][4];       // L2/3 table: spike u8 quads
  __shared__ __align__(4)  uint8_t  s_lds[3][200][4];
  __shared__ __align__(16) float    mem_lds[3][200][4];
  __shared__ float  w4_lds[12][201];
  __shared__ float2 bbL[3 * ROWS];
  __shared__ float  saL[3 * 200];

  const int tid = threadIdx.x;
  const int bg  = blockIdx.x;          // batches bg*4 .. bg*4+3

  for (int idx = tid; idx < 600; idx += NTHR) {
    reinterpret_cast<uint32_t*>(&s_lds[0][0][0])[idx] = 0u;
    reinterpret_cast<float4*>(&mem_lds[0][0][0])[idx] = make_float4(0.f, 0.f, 0.f, 0.f);
  }
  for (int idx = tid; idx < 12 * 200; idx += NTHR)
    w4_lds[idx / 200][idx % 200] = W4[idx];
  for (int idx = tid; idx < 3 * ROWS; idx += NTHR) bbL[idx] = bbG[idx];
  for (int idx = tid; idx < 3 * 200; idx += NTHR) saL[idx] = saG[idx];

  float d[3][2][4];
#pragma unroll
  for (int l = 0; l < 3; ++l)
#pragma unroll
    for (int i = 0; i < 2; ++i)
#pragma unroll
      for (int b = 0; b < 4; ++b) d[l][i][b] = 0.0f;

  const int r1 = tid + 576;            // slot-1 row for tid>=448
  float m4_reg = 0.0f, m4_acc = 0.0f, a4 = 0.0f, b4r = 0.0f;
  if (tid < 192) { const int o = (tid >> 2) >> 2; a4 = sigmoidf(tm4[o]); b4r = b4[o]; }
  __syncthreads();

  const uint8_t* k1b = reinterpret_cast<const uint8_t*>(&k1f[0]);
  const uint8_t* k2b = reinterpret_cast<const uint8_t*>(&k23[0][0]);

  for (int t = 0; t < T_STEPS; ++t) {
    // ---- build k1 = [x_t | s1(old)] -----------------------------------
    if (tid < 480) {
      const int bat = tid / 120, cf = tid - bat * 120;
      const int c = cf / 40, f = cf - c * 40;
      reinterpret_cast<float*>(&k1f[cf])[bat] =
          x[(((size_t)(bg * 4 + bat) * 3 + c) * T_STEPS + t) * 40 + f];
    }
    if (tid < 200) {
      const uint32_t so = *reinterpret_cast<const uint32_t*>(&s_lds[0][tid][0]);
      k1f[120 + tid] = make_float4((float)(so & 0xffu), (float)((so >> 8) & 0xffu),
                                   (float)((so >> 16) & 0xffu), (float)(so >> 24));
    }
    __syncthreads();
    slot_compute<NP1, true>(tid, tid, w2G, c2G, k1b, bbL, saL,
                            d[0][0], s_lds[0], mem_lds[0]);
    if (tid >= 448)
      slot_compute<NP1, true>(tid, r1, w2G, c2G, k1b, bbL, saL,
                              d[0][1], s_lds[0], mem_lds[0]);
    __syncthreads();
    // ---- build k2 = [s1(new) | s2(old)] (u32 copies) ------------------
    if (tid < 200)
      reinterpret_cast<uint32_t*>(&k23[0][0])[tid] =
          reinterpret_cast<const uint32_t*>(&s_lds[0][0][0])[tid];
    else if (tid < 400)
      reinterpret_cast<uint32_t*>(&k23[0][0])[tid] =
          reinterpret_cast<const uint32_t*>(&s_lds[1][0][0])[tid - 200];
    __syncthreads();
    slot_compute<NP23, false>(tid, tid, w2G + PO2, c2G + PO2, k2b, bbL + ROWS, saL + 200,
                              d[1][0], s_lds[1], mem_lds[1]);
    if (tid >= 448)
      slot_compute<NP23, false>(tid, r1, w2G + PO2, c2G + PO2, k2b, bbL + ROWS, saL + 200,
                                d[1][1], s_lds[1], mem_lds[1]);
    __syncthreads();
    // ---- build k3 = [s2(new) | s3(old)] -------------------------------
    if (tid < 200)
      reinterpret_cast<uint32_t*>(&k23[0][0])[tid] =
          reinterpret_cast<const uint32_t*>(&s_lds[1][0][0])[tid];
    else if (tid < 400)
      reinterpret_cast<uint32_t*>(&k23[0][0])[tid] =
          reinterpret_cast<const uint32_t*>(&s_lds[2][0][0])[tid - 200];
    __syncthreads();
    slot_compute<NP23, false>(tid, tid, w2G + PO3, c2G + PO3, k2b, bbL + 2 * ROWS, saL + 400,
                              d[2][0], s_lds[2], mem_lds[2]);
    if (tid >= 448)
      slot_compute<NP23, false>(tid, r1, w2G + PO3, c2G + PO3, k2b, bbL + 2 * ROWS, saL + 400,
                                d[2][1], s_lds[2], mem_lds[2]);
    __syncthreads();
    // ---- leaky readout: 192 threads (waves 0-2), 4 lanes per (o,bat) --
    // (reassociated partial sums -- verified absmax 0.0 in rounds 11/12)
    if (tid < 192) {
      const int sub = tid & 3, pair = tid >> 2, o = pair >> 2, bat = pair & 3;
      float part = 0.0f;
#pragma unroll 10
      for (int m = 0; m < 50; ++m) {
        const int n = 4 * m + sub;
        part = fmaf(w4_lds[o][n], (float)s_lds[2][n][bat], part);
      }
      part += __shfl_xor(part, 1);
      part += __shfl_xor(part, 2);
      const float dot = b4r + part;
      m4_reg = a4 * m4_reg + (1.0f - a4) * dot;
      m4_acc += m4_reg;
    }
    // no trailing barrier: stage-k1(t+1) touches only k1f / s_lds[0];
    // readout touches only s_lds[2] / w4_lds.
  }

  // ---- log_softmax(acc / T) -------------------------------------------
  __syncthreads();
  if (tid < 192 && (tid & 3) == 0) {
    const int pair = tid >> 2, o = pair >> 2, bat = pair & 3;
    reinterpret_cast<float*>(&k1f[o])[bat] = m4_acc * (1.0f / (float)T_STEPS);
  }
  __syncthreads();
  if (tid < 4) {
    const int bat = tid;
    float v[12], mx = -1e30f;
#pragma unroll
    for (int o = 0; o < 12; ++o) {
      v[o] = reinterpret_cast<float*>(&k1f[o])[bat];
      mx = fmaxf(mx, v[o]);
    }
    float s = 0.0f;
#pragma unroll
    for (int o = 0; o < 12; ++o) s += expf(v[o] - mx);
    const float ls = logf(s);
#pragma unroll
    for (int o = 0; o < 12; ++o)
      out[((size_t)(bg * 4 + bat)) * 12 + o] = v[o] - mx - ls;
  }
}

// ---------------------------------------------------------------------------
extern "C" void kernel_launch(void* const* d_in, const int* in_sizes, int n_in,
                              void* d_out, int out_size, void* d_ws, size_t ws_size,
                              hipStream_t stream) {
  (void)in_sizes; (void)n_in; (void)out_size; (void)ws_size;
  const float* x   = (const float*)d_in[0];
  const float* W1  = (const float*)d_in[1];
  const float* b1  = (const float*)d_in[2];
  const float* tm1 = (const float*)d_in[3];
  const float* tn1 = (const float*)d_in[4];
  const float* W2  = (const float*)d_in[5];
  const float* b2  = (const float*)d_in[6];
  const float* tm2 = (const float*)d_in[7];
  const float* tn2 = (const float*)d_in[8];
  const float* W3  = (const float*)d_in[9];
  const float* b3  = (const float*)d_in[10];
  const float* tm3 = (const float*)d_in[11];
  const float* tn3 = (const float*)d_in[12];
  const float* W4  = (const float*)d_in[13];
  const float* b4  = (const float*)d_in[14];
  const float* tm4 = (const float*)d_in[15];

  uint8_t* ws = (uint8_t*)d_ws;
  const float2*   w2G = (const float2*)(ws + W2_OFF);
  const uint32_t* c2G = (const uint32_t*)(ws + C2_OFF);
  const float2*   bbG = (const float2*)(ws + BB_OFF);
  const float*    saG = (const float*)(ws + SA_OFF);

  prep_kernel<<<dim3(19), dim3(256), 0, stream>>>(
      W1, W2, W3, b1, tn1, tm1, b2, tn2, tm2, b3, tn3, tm3, ws);
  snn_main<<<dim3(NBLK), dim3(NTHR), 0, stream>>>(
      x, W4, b4, tm4, w2G, c2G, bbG, saG, (float*)d_out);
}

// Round 14
// 3147.361 us; speedup vs baseline: 1.9328x; 1.0130x over previous
//
#include <hip/hip_runtime.h>
#include <stdint.h>

#define T_STEPS 101
#define ROWS 1600
#define NTHR 1024
#define NBLK 256            /* 4 batches per block, 1024 batches total */
#define NP1 20              /* L1: 40 nz = 20 pairs */
#define NP23 25             /* L2/3: 50 nz = 25 pairs */
#define PO2 (NP1 * ROWS)               /* 32000 pairs */
#define PO3 (PO2 + NP23 * ROWS)        /* 72000 */
#define NPTOT (PO3 + NP23 * ROWS)      /* 112000 pairs */

/* ws byte offsets */
#define W2_OFF 0
#define C2_OFF (NPTOT * 8)                   /* 896000  */
#define BB_OFF (C2_OFF + NPTOT * 4)          /* 1344000 */
#define SA_OFF (BB_OFF + 3 * ROWS * 8)       /* 1382400 */

__device__ __forceinline__ float sigmoidf(float v) { return 1.0f / (1.0f + expf(-v)); }

// ---------------------------------------------------------------------------
// Prep (unchanged from round 13): paired CSR streams, ascending col order.
// Offset scale: L1 col*16 (float4 k1 table), L2/3 col*4 (u8-quad tables).
// ---------------------------------------------------------------------------
__global__ void prep_kernel(const float* __restrict__ W1, const float* __restrict__ W2,
                            const float* __restrict__ W3,
                            const float* __restrict__ b1, const float* __restrict__ tn1,
                            const float* __restrict__ tm1,
                            const float* __restrict__ b2, const float* __restrict__ tn2,
                            const float* __restrict__ tm2,
                            const float* __restrict__ b3, const float* __restrict__ tn3,
                            const float* __restrict__ tm3,
                            uint8_t* __restrict__ ws) {
  int gid = blockIdx.x * blockDim.x + threadIdx.x;
  if (gid >= 3 * ROWS) return;
  int l = gid / ROWS, r = gid - l * ROWS;
  const float *W, *bb, *tn, *tm; int in_f, knz, np, poff, scale;
  if (l == 0)      { W = W1; bb = b1; tn = tn1; tm = tm1; in_f = 320; knz = 40; np = NP1;  poff = 0;   scale = 16; }
  else if (l == 1) { W = W2; bb = b2; tn = tn2; tm = tm2; in_f = 400; knz = 50; np = NP23; poff = PO2; scale = 4; }
  else             { W = W3; bb = b3; tn = tn3; tm = tm3; in_f = 400; knz = 50; np = NP23; poff = PO3; scale = 4; }
  float2* w2 = (float2*)(ws + W2_OFF) + poff;
  uint32_t* c2 = (uint32_t*)(ws + C2_OFF) + poff;
  float wl[52]; uint32_t cl[52];
  int cnt = 0;
  for (int col = 0; col < in_f; ++col) {
    float w = W[(size_t)r * in_f + col];
    if (w != 0.0f && cnt < knz) { wl[cnt] = w; cl[cnt] = (uint32_t)(col * scale); ++cnt; }
  }
  for (; cnt < 2 * np; ++cnt) { wl[cnt] = 0.0f; cl[cnt] = 0u; }
  for (int p = 0; p < np; ++p) {
    w2[p * ROWS + r] = make_float2(wl[2 * p], wl[2 * p + 1]);
    c2[p * ROWS + r] = cl[2 * p] | (cl[2 * p + 1] << 16);
  }
  ((float2*)(ws + BB_OFF))[l * ROWS + r] = make_float2(sigmoidf(tn[r]), bb[r]);
  if (r < 200) ((float*)(ws + SA_OFF))[l * 200 + r] = sigmoidf(tm[r]);
}

// ---------------------------------------------------------------------------
// One row-slot, 4 batch lanes (round-13's verified gather + state update).
// Leader additionally writes the spike word into the consumer tables
// (template-selected): WA -> spA[n], WB -> spB[n], WK1 -> float4 to k1n[120+n].
// ---------------------------------------------------------------------------
template<int NP, bool F32, bool WA, bool WB, bool WK1>
__device__ __forceinline__ void slot_compute(
    int tid, int r,
    const float2* __restrict__ w2, const uint32_t* __restrict__ c2,
    const uint8_t* __restrict__ ktab,
    const float2* __restrict__ bbL, const float* __restrict__ saL,
    float (&dreg)[4], uint8_t (*s_l)[4], float (*mem_l)[4],
    uint8_t (*spA)[4], uint8_t (*spB)[4], float4* k1n)
{
  const float2 bb = bbL[r];
  const float bt = bb.x;
  float a0 = bb.y, a1 = bb.y, a2 = bb.y, a3 = bb.y;
  const float2* wp = w2 + r;
  const uint32_t* cp = c2 + r;
#pragma unroll 5
  for (int p = 0; p < NP; ++p) {
    const float2 w = wp[(size_t)p * ROWS];
    const uint32_t c = cp[(size_t)p * ROWS];
    if constexpr (F32) {
      { const float4 kv = *reinterpret_cast<const float4*>(ktab + (c & 0xffffu));
        a0 = fmaf(w.x, kv.x, a0); a1 = fmaf(w.x, kv.y, a1);
        a2 = fmaf(w.x, kv.z, a2); a3 = fmaf(w.x, kv.w, a3); }
      { const float4 kv = *reinterpret_cast<const float4*>(ktab + (c >> 16));
        a0 = fmaf(w.y, kv.x, a0); a1 = fmaf(w.y, kv.y, a1);
        a2 = fmaf(w.y, kv.z, a2); a3 = fmaf(w.y, kv.w, a3); }
    } else {
      { const uint32_t q = *reinterpret_cast<const uint32_t*>(ktab + (c & 0xffffu));
        a0 = fmaf(w.x, (float)(q & 0xffu), a0);
        a1 = fmaf(w.x, (float)((q >> 8) & 0xffu), a1);
        a2 = fmaf(w.x, (float)((q >> 16) & 0xffu), a2);
        a3 = fmaf(w.x, (float)(q >> 24), a3); }
      { const uint32_t q = *reinterpret_cast<const uint32_t*>(ktab + (c >> 16));
        a0 = fmaf(w.y, (float)(q & 0xffu), a0);
        a1 = fmaf(w.y, (float)((q >> 8) & 0xffu), a1);
        a2 = fmaf(w.y, (float)((q >> 16) & 0xffu), a2);
        a3 = fmaf(w.y, (float)(q >> 24), a3); }
    }
  }
  const float ob = 1.0f - bt;
  float d0 = fmaf(bt, dreg[0], ob * a0);
  float d1 = fmaf(bt, dreg[1], ob * a1);
  float d2 = fmaf(bt, dreg[2], ob * a2);
  float d3 = fmaf(bt, dreg[3], ob * a3);
  dreg[0] = d0; dreg[1] = d1; dreg[2] = d2; dreg[3] = d3;
  d0 += __shfl_xor(d0, 1); d0 += __shfl_xor(d0, 2); d0 += __shfl_xor(d0, 4);
  d1 += __shfl_xor(d1, 1); d1 += __shfl_xor(d1, 2); d1 += __shfl_xor(d1, 4);
  d2 += __shfl_xor(d2, 1); d2 += __shfl_xor(d2, 2); d2 += __shfl_xor(d2, 4);
  d3 += __shfl_xor(d3, 1); d3 += __shfl_xor(d3, 2); d3 += __shfl_xor(d3, 4);
  if ((tid & 7) == 0) {
    const int n = r >> 3;
    const float al = saL[n], oa = 1.0f - al;
    float4 mv = *reinterpret_cast<float4*>(&mem_l[n][0]);
    const uint32_t so = *reinterpret_cast<uint32_t*>(&s_l[n][0]);
    const float m0 = fmaf(mv.x - (float)(so & 0xffu),         al, oa * d0);
    const float m1 = fmaf(mv.y - (float)((so >> 8) & 0xffu),  al, oa * d1);
    const float m2 = fmaf(mv.z - (float)((so >> 16) & 0xffu), al, oa * d2);
    const float m3 = fmaf(mv.w - (float)(so >> 24),           al, oa * d3);
    *reinterpret_cast<float4*>(&mem_l[n][0]) = make_float4(m0, m1, m2, m3);
    const uint32_t sn = (m0 > 1.0f ? 1u : 0u) | (m1 > 1.0f ? 0x100u : 0u)
                      | (m2 > 1.0f ? 0x10000u : 0u) | (m3 > 1.0f ? 0x1000000u : 0u);
    *reinterpret_cast<uint32_t*>(&s_l[n][0]) = sn;
    if constexpr (WA) *reinterpret_cast<uint32_t*>(&spA[n][0]) = sn;
    if constexpr (WB) *reinterpret_cast<uint32_t*>(&spB[n][0]) = sn;
    if constexpr (WK1)
      k1n[120 + n] = make_float4(m0 > 1.0f ? 1.0f : 0.0f, m1 > 1.0f ? 1.0f : 0.0f,
                                 m2 > 1.0f ? 1.0f : 0.0f, m3 > 1.0f ? 1.0f : 0.0f);
  }
}

// ---------------------------------------------------------------------------
// Main kernel: 256 blocks x 1024 threads, 4 batches/block. 3 phases/step
// (was 7): spike producers write all consumer tables directly (double-
// buffered), x-staging and readout fold into phase A on the idle waves.
//   phase A: L1 gather | slot1 on waves 7-15 | x(t+1) stage on waves 3-6 |
//            readout(t-1) on waves 0-2        -> barrier
//   phase B: L2 gather (+slot1)               -> barrier
//   phase C: L3 gather (+slot1)               -> barrier
// ---------------------------------------------------------------------------
__global__ void __launch_bounds__(NTHR)
snn_main(const float* __restrict__ x,
         const float* __restrict__ W4, const float* __restrict__ b4,
         const float* __restrict__ tm4,
         const float2* __restrict__ w2G, const uint32_t* __restrict__ c2G,
         const float2* __restrict__ bbG, const float* __restrict__ saG,
         float* __restrict__ out)
{
  __shared__ __align__(16) float4   k1f[2][320];       // dbuf: x | s1 (f32 quads)
  __shared__ __align__(4)  uint8_t  k2tab[2][400][4];  // dbuf: [s1 | s2] u8 quads
  __shared__ __align__(4)  uint8_t  k3tab[2][400][4];  // dbuf: [s2 | s3] u8 quads
  __shared__ __align__(4)  uint8_t  s_lds[3][200][4];
  __shared__ __align__(16) float    mem_lds[3][200][4];
  __shared__ float  w4_lds[12][201];
  __shared__ float2 bbL[3 * ROWS];
  __shared__ float  saL[3 * 200];
  __shared__ float  smx[12][4];

  const int tid = threadIdx.x;
  const int bg  = blockIdx.x;          // batches bg*4 .. bg*4+3

  for (int idx = tid; idx < 600; idx += NTHR) {
    reinterpret_cast<uint32_t*>(&s_lds[0][0][0])[idx] = 0u;
    reinterpret_cast<float4*>(&mem_lds[0][0][0])[idx] = make_float4(0.f, 0.f, 0.f, 0.f);
  }
  for (int idx = tid; idx < 800; idx += NTHR) {        // zero both k2/k3 buffers
    reinterpret_cast<uint32_t*>(&k2tab[0][0][0])[idx] = 0u;
    reinterpret_cast<uint32_t*>(&k3tab[0][0][0])[idx] = 0u;
  }
  for (int idx = tid; idx < 200; idx += NTHR)          // s1(-1) = 0 in k1f[0]
    k1f[0][120 + idx] = make_float4(0.f, 0.f, 0.f, 0.f);
  for (int idx = tid; idx < 12 * 200; idx += NTHR)
    w4_lds[idx / 200][idx % 200] = W4[idx];
  for (int idx = tid; idx < 3 * ROWS; idx += NTHR) bbL[idx] = bbG[idx];
  for (int idx = tid; idx < 3 * 200; idx += NTHR) saL[idx] = saG[idx];
  // stage x(0) into k1f[0][0..119]
  if (tid < 480) {
    const int bat = tid / 120, cf = tid - bat * 120;
    const int c = cf / 40, f = cf - c * 40;
    reinterpret_cast<float*>(&k1f[0][cf])[bat] =
        x[(((size_t)(bg * 4 + bat) * 3 + c) * T_STEPS) * 40 + f];
  }

  float d[3][2][4];
#pragma unroll
  for (int l = 0; l < 3; ++l)
#pragma unroll
    for (int i = 0; i < 2; ++i)
#pragma unroll
      for (int b = 0; b < 4; ++b) d[l][i][b] = 0.0f;

  const int r1 = tid + 576;            // slot-1 row for tid>=448
  // readout constants (waves 0-2)
  float m4_reg = 0.0f, m4_acc = 0.0f, a4 = 0.0f, b4r = 0.0f;
  if (tid < 192) { const int o = tid >> 4; a4 = sigmoidf(tm4[o]); b4r = b4[o]; }
  // x-staging pointers (waves 3-6): up to 2 elements each
  const float* xpA = nullptr; const float* xpB = nullptr;
  int dofA = 0, dofB = 0;              // float-offset into a k1f buffer
  if (tid >= 192 && tid < 448) {
    const int q0 = tid - 192;
    { const int bat = q0 / 120, cf = q0 - bat * 120;
      const int c = cf / 40, f = cf - c * 40;
      xpA = x + (((size_t)(bg * 4 + bat) * 3 + c) * T_STEPS) * 40 + f;
      dofA = cf * 4 + bat; }
    const int q1 = q0 + 256;
    if (q1 < 480) {
      const int bat = q1 / 120, cf = q1 - bat * 120;
      const int c = cf / 40, f = cf - c * 40;
      xpB = x + (((size_t)(bg * 4 + bat) * 3 + c) * T_STEPS) * 40 + f;
      dofB = cf * 4 + bat;
    }
  }
  __syncthreads();

  for (int t = 0; t < T_STEPS; ++t) {
    const int cur = t & 1, nxt = cur ^ 1;
    const uint8_t* k1b = reinterpret_cast<const uint8_t*>(&k1f[cur][0]);
    const uint8_t* k2b = reinterpret_cast<const uint8_t*>(&k2tab[cur][0][0]);
    const uint8_t* k3b = reinterpret_cast<const uint8_t*>(&k3tab[cur][0][0]);
    // ---- phase A: issue x(t+1) loads early (waves 3-6) -----------------
    float xv0 = 0.f, xv1 = 0.f;
    const bool doX = (tid >= 192 && tid < 448) && (t + 1 < T_STEPS);
    if (doX) {
      xv0 = xpA[(t + 1) * 40];
      if (xpB) xv1 = xpB[(t + 1) * 40];
    }
    // L1 gather: leaders write s1 -> k2tab[cur][0..199] and f32 quad ->
    // k1f[nxt][120..319]
    slot_compute<NP1, true, true, false, true>(
        tid, tid, w2G, c2G, k1b, bbL, saL, d[0][0], s_lds[0], mem_lds[0],
        k2tab[cur], k2tab[cur], k1f[nxt]);
    if (tid >= 448) {
      slot_compute<NP1, true, true, false, true>(
          tid, r1, w2G, c2G, k1b, bbL, saL, d[0][1], s_lds[0], mem_lds[0],
          k2tab[cur], k2tab[cur], k1f[nxt]);
    } else if (tid >= 192) {
      if (doX) {
        reinterpret_cast<float*>(&k1f[nxt][0])[dofA] = xv0;
        if (xpB) reinterpret_cast<float*>(&k1f[nxt][0])[dofB] = xv1;
      }
    } else if (t > 0) {
      // readout for step t-1 (s_lds[2] still holds s3(t-1))
      const int sub = tid & 3, pair = tid >> 2, o = pair >> 4, bat = pair & 3;
      // NOTE: o = (tid>>2)>>4? -- see mapping below (12 outputs x 4 bats x 4 subs)
      float part = 0.0f;
#pragma unroll 10
      for (int m = 0; m < 50; ++m) {
        const int n = 4 * m + sub;
        part = fmaf(w4_lds[(tid >> 4)][n], (float)s_lds[2][n][(tid >> 2) & 3], part);
      }
      part += __shfl_xor(part, 1);
      part += __shfl_xor(part, 2);
      const float dot = b4r + part;
      m4_reg = a4 * m4_reg + (1.0f - a4) * dot;
      m4_acc += m4_reg;
    }
    __syncthreads();
    // ---- phase B: L2 (leaders: s2 -> k3tab[cur][0..199], k2tab[nxt][200..]) --
    slot_compute<NP23, false, true, true, false>(
        tid, tid, w2G + PO2, c2G + PO2, k2b, bbL + ROWS, saL + 200,
        d[1][0], s_lds[1], mem_lds[1], k3tab[cur], k2tab[nxt] + 200, nullptr);
    if (tid >= 448)
      slot_compute<NP23, false, true, true, false>(
          tid, r1, w2G + PO2, c2G + PO2, k2b, bbL + ROWS, saL + 200,
          d[1][1], s_lds[1], mem_lds[1], k3tab[cur], k2tab[nxt] + 200, nullptr);
    __syncthreads();
    // ---- phase C: L3 (leaders: s3 -> k3tab[nxt][200..399]) -------------
    slot_compute<NP23, false, false, true, false>(
        tid, tid, w2G + PO3, c2G + PO3, k3b, bbL + 2 * ROWS, saL + 400,
        d[2][0], s_lds[2], mem_lds[2], k3tab[cur], k3tab[nxt] + 200, nullptr);
    if (tid >= 448)
      slot_compute<NP23, false, false, true, false>(
          tid, r1, w2G + PO3, c2G + PO3, k3b, bbL + 2 * ROWS, saL + 400,
          d[2][1], s_lds[2], mem_lds[2], k3tab[cur], k3tab[nxt] + 200, nullptr);
    __syncthreads();
  }

  // ---- final readout (t = 100) ----------------------------------------
  if (tid < 192) {
    const int sub = tid & 3;
    float part = 0.0f;
#pragma unroll 10
    for (int m = 0; m < 50; ++m) {
      const int n = 4 * m + sub;
      part = fmaf(w4_lds[(tid >> 4)][n], (float)s_lds[2][n][(tid >> 2) & 3], part);
    }
    part += __shfl_xor(part, 1);
    part += __shfl_xor(part, 2);
    const float dot = b4r + part;
    m4_reg = a4 * m4_reg + (1.0f - a4) * dot;
    m4_acc += m4_reg;
    if ((tid & 3) == 0)
      smx[tid >> 4][(tid >> 2) & 3] = m4_acc * (1.0f / (float)T_STEPS);
  }
  __syncthreads();
  if (tid < 4) {
    const int bat = tid;
    float v[12], mx = -1e30f;
#pragma unroll
    for (int o = 0; o < 12; ++o) { v[o] = smx[o][bat]; mx = fmaxf(mx, v[o]); }
    float s = 0.0f;
#pragma unroll
    for (int o = 0; o < 12; ++o) s += expf(v[o] - mx);
    const float ls = logf(s);
#pragma unroll
    for (int o = 0; o < 12; ++o)
      out[((size_t)(bg * 4 + bat)) * 12 + o] = v[o] - mx - ls;
  }
}

// ---------------------------------------------------------------------------
extern "C" void kernel_launch(void* const* d_in, const int* in_sizes, int n_in,
                              void* d_out, int out_size, void* d_ws, size_t ws_size,
                              hipStream_t stream) {
  (void)in_sizes; (void)n_in; (void)out_size; (void)ws_size;
  const float* x   = (const float*)d_in[0];
  const float* W1  = (const float*)d_in[1];
  const float* b1  = (const float*)d_in[2];
  const float* tm1 = (const float*)d_in[3];
  const float* tn1 = (const float*)d_in[4];
  const float* W2  = (const float*)d_in[5];
  const float* b2  = (const float*)d_in[6];
  const float* tm2 = (const float*)d_in[7];
  const float* tn2 = (const float*)d_in[8];
  const float* W3  = (const float*)d_in[9];
  const float* b3  = (const float*)d_in[10];
  const float* tm3 = (const float*)d_in[11];
  const float* tn3 = (const float*)d_in[12];
  const float* W4  = (const float*)d_in[13];
  const float* b4  = (const float*)d_in[14];
  const float* tm4 = (const float*)d_in[15];

  uint8_t* ws = (uint8_t*)d_ws;
  const float2*   w2G = (const float2*)(ws + W2_OFF);
  const uint32_t* c2G = (const uint32_t*)(ws + C2_OFF);
  const float2*   bbG = (const float2*)(ws + BB_OFF);
  const float*    saG = (const float*)(ws + SA_OFF);

  prep_kernel<<<dim3(19), dim3(256), 0, stream>>>(
      W1, W2, W3, b1, tn1, tm1, b2, tn2, tm2, b3, tn3, tm3, ws);
  snn_main<<<dim3(NBLK), dim3(NTHR), 0, stream>>>(
      x, W4, b4, tm4, w2G, c2G, bbG, saG, (float*)d_out);
}

// Round 15
// 2648.427 us; speedup vs baseline: 2.2970x; 1.1884x over previous
//
#include <hip/hip_runtime.h>
#include <stdint.h>

#define T_STEPS 101
#define ROWS 1600
#define NTHR 1024
#define NBLK 256            /* 4 batches per block, 1024 batches total */
#define NP1 20              /* L1: 40 nz = 20 pairs */
#define NP23 25             /* L2/3: 50 nz = 25 pairs */
#define PO2 (NP1 * ROWS)               /* 32000 pairs */
#define PO3 (PO2 + NP23 * ROWS)        /* 72000 */
#define NPTOT (PO3 + NP23 * ROWS)      /* 112000 pairs */

/* ws byte offsets */
#define W2_OFF 0
#define C2_OFF (NPTOT * 8)                   /* 896000  */
#define BB_OFF (C2_OFF + NPTOT * 4)          /* 1344000 */
#define SA_OFF (BB_OFF + 3 * ROWS * 8)       /* 1382400 */

__device__ __forceinline__ float sigmoidf(float v) { return 1.0f / (1.0f + expf(-v)); }

// ---------------------------------------------------------------------------
// Prep (unchanged from rounds 13/14): paired CSR streams, ascending col order.
// Offset scale: L1 col*16 (float4 k1 table), L2/3 col*4 (u8-quad tables).
// ---------------------------------------------------------------------------
__global__ void prep_kernel(const float* __restrict__ W1, const float* __restrict__ W2,
                            const float* __restrict__ W3,
                            const float* __restrict__ b1, const float* __restrict__ tn1,
                            const float* __restrict__ tm1,
                            const float* __restrict__ b2, const float* __restrict__ tn2,
                            const float* __restrict__ tm2,
                            const float* __restrict__ b3, const float* __restrict__ tn3,
                            const float* __restrict__ tm3,
                            uint8_t* __restrict__ ws) {
  int gid = blockIdx.x * blockDim.x + threadIdx.x;
  if (gid >= 3 * ROWS) return;
  int l = gid / ROWS, r = gid - l * ROWS;
  const float *W, *bb, *tn, *tm; int in_f, knz, np, poff, scale;
  if (l == 0)      { W = W1; bb = b1; tn = tn1; tm = tm1; in_f = 320; knz = 40; np = NP1;  poff = 0;   scale = 16; }
  else if (l == 1) { W = W2; bb = b2; tn = tn2; tm = tm2; in_f = 400; knz = 50; np = NP23; poff = PO2; scale = 4; }
  else             { W = W3; bb = b3; tn = tn3; tm = tm3; in_f = 400; knz = 50; np = NP23; poff = PO3; scale = 4; }
  float2* w2 = (float2*)(ws + W2_OFF) + poff;
  uint32_t* c2 = (uint32_t*)(ws + C2_OFF) + poff;
  float wl[52]; uint32_t cl[52];
  int cnt = 0;
  for (int col = 0; col < in_f; ++col) {
    float w = W[(size_t)r * in_f + col];
    if (w != 0.0f && cnt < knz) { wl[cnt] = w; cl[cnt] = (uint32_t)(col * scale); ++cnt; }
  }
  for (; cnt < 2 * np; ++cnt) { wl[cnt] = 0.0f; cl[cnt] = 0u; }
  for (int p = 0; p < np; ++p) {
    w2[p * ROWS + r] = make_float2(wl[2 * p], wl[2 * p + 1]);
    c2[p * ROWS + r] = cl[2 * p] | (cl[2 * p + 1] << 16);
  }
  ((float2*)(ws + BB_OFF))[l * ROWS + r] = make_float2(sigmoidf(tn[r]), bb[r]);
  if (r < 200) ((float*)(ws + SA_OFF))[l * 200 + r] = sigmoidf(tm[r]);
}

// ---------------------------------------------------------------------------
// One row-slot, 4 batch lanes (rounds 13/14's verified gather + state update).
// Leader writes spike word into consumer tables: WA -> spA[n], WB -> spB[n],
// WK1 -> float4 to k1n[120+n].
// ---------------------------------------------------------------------------
template<int NP, bool F32, bool WA, bool WB, bool WK1>
__device__ __forceinline__ void slot_compute(
    int tid, int r,
    const float2* __restrict__ w2, const uint32_t* __restrict__ c2,
    const uint8_t* __restrict__ ktab,
    const float2* __restrict__ bbL, const float* __restrict__ saL,
    float (&dreg)[4], uint8_t (*s_l)[4], float (*mem_l)[4],
    uint8_t (*spA)[4], uint8_t (*spB)[4], float4* k1n)
{
  const float2 bb = bbL[r];
  const float bt = bb.x;
  float a0 = bb.y, a1 = bb.y, a2 = bb.y, a3 = bb.y;
  const float2* wp = w2 + r;
  const uint32_t* cp = c2 + r;
#pragma unroll 5
  for (int p = 0; p < NP; ++p) {
    const float2 w = wp[(size_t)p * ROWS];
    const uint32_t c = cp[(size_t)p * ROWS];
    if constexpr (F32) {
      { const float4 kv = *reinterpret_cast<const float4*>(ktab + (c & 0xffffu));
        a0 = fmaf(w.x, kv.x, a0); a1 = fmaf(w.x, kv.y, a1);
        a2 = fmaf(w.x, kv.z, a2); a3 = fmaf(w.x, kv.w, a3); }
      { const float4 kv = *reinterpret_cast<const float4*>(ktab + (c >> 16));
        a0 = fmaf(w.y, kv.x, a0); a1 = fmaf(w.y, kv.y, a1);
        a2 = fmaf(w.y, kv.z, a2); a3 = fmaf(w.y, kv.w, a3); }
    } else {
      { const uint32_t q = *reinterpret_cast<const uint32_t*>(ktab + (c & 0xffffu));
        a0 = fmaf(w.x, (float)(q & 0xffu), a0);
        a1 = fmaf(w.x, (float)((q >> 8) & 0xffu), a1);
        a2 = fmaf(w.x, (float)((q >> 16) & 0xffu), a2);
        a3 = fmaf(w.x, (float)(q >> 24), a3); }
      { const uint32_t q = *reinterpret_cast<const uint32_t*>(ktab + (c >> 16));
        a0 = fmaf(w.y, (float)(q & 0xffu), a0);
        a1 = fmaf(w.y, (float)((q >> 8) & 0xffu), a1);
        a2 = fmaf(w.y, (float)((q >> 16) & 0xffu), a2);
        a3 = fmaf(w.y, (float)(q >> 24), a3); }
    }
  }
  const float ob = 1.0f - bt;
  float d0 = fmaf(bt, dreg[0], ob * a0);
  float d1 = fmaf(bt, dreg[1], ob * a1);
  float d2 = fmaf(bt, dreg[2], ob * a2);
  float d3 = fmaf(bt, dreg[3], ob * a3);
  dreg[0] = d0; dreg[1] = d1; dreg[2] = d2; dreg[3] = d3;
  d0 += __shfl_xor(d0, 1); d0 += __shfl_xor(d0, 2); d0 += __shfl_xor(d0, 4);
  d1 += __shfl_xor(d1, 1); d1 += __shfl_xor(d1, 2); d1 += __shfl_xor(d1, 4);
  d2 += __shfl_xor(d2, 1); d2 += __shfl_xor(d2, 2); d2 += __shfl_xor(d2, 4);
  d3 += __shfl_xor(d3, 1); d3 += __shfl_xor(d3, 2); d3 += __shfl_xor(d3, 4);
  if ((tid & 7) == 0) {
    const int n = r >> 3;
    const float al = saL[n], oa = 1.0f - al;
    float4 mv = *reinterpret_cast<float4*>(&mem_l[n][0]);
    const uint32_t so = *reinterpret_cast<uint32_t*>(&s_l[n][0]);
    const float m0 = fmaf(mv.x - (float)(so & 0xffu),         al, oa * d0);
    const float m1 = fmaf(mv.y - (float)((so >> 8) & 0xffu),  al, oa * d1);
    const float m2 = fmaf(mv.z - (float)((so >> 16) & 0xffu), al, oa * d2);
    const float m3 = fmaf(mv.w - (float)(so >> 24),           al, oa * d3);
    *reinterpret_cast<float4*>(&mem_l[n][0]) = make_float4(m0, m1, m2, m3);
    const uint32_t sn = (m0 > 1.0f ? 1u : 0u) | (m1 > 1.0f ? 0x100u : 0u)
                      | (m2 > 1.0f ? 0x10000u : 0u) | (m3 > 1.0f ? 0x1000000u : 0u);
    *reinterpret_cast<uint32_t*>(&s_l[n][0]) = sn;
    if constexpr (WA) *reinterpret_cast<uint32_t*>(&spA[n][0]) = sn;
    if constexpr (WB) *reinterpret_cast<uint32_t*>(&spB[n][0]) = sn;
    if constexpr (WK1)
      k1n[120 + n] = make_float4(m0 > 1.0f ? 1.0f : 0.0f, m1 > 1.0f ? 1.0f : 0.0f,
                                 m2 > 1.0f ? 1.0f : 0.0f, m3 > 1.0f ? 1.0f : 0.0f);
  }
}

// ---------------------------------------------------------------------------
// Main kernel: 256 blocks x 1024 threads, 4 batches/block, LAYER-SKEWED
// pipeline: super-step u runs {L1(u), L2(u-1), L3(u-2), readout(u-3),
// x-stage(u+1)} in ONE barrier phase. 75 wave-slots grid-strided over 16
// waves (waves 0-10: 5 slots; 11-15: 4 slots + readout / x-staging).
// Critical path 5 slot-times/step (was 6) and 1 barrier/step (was 3).
// Parity audit: every table written at parity p in the phase before its
// parity-p read; no same-phase same-parity read/write overlap.
// ---------------------------------------------------------------------------
__global__ void __launch_bounds__(NTHR)
snn_main(const float* __restrict__ x,
         const float* __restrict__ W4, const float* __restrict__ b4,
         const float* __restrict__ tm4,
         const float2* __restrict__ w2G, const uint32_t* __restrict__ c2G,
         const float2* __restrict__ bbG, const float* __restrict__ saG,
         float* __restrict__ out)
{
  __shared__ __align__(16) float4   k1f[2][320];       // parity: x(t) | s1(t-1)
  __shared__ __align__(4)  uint8_t  k2tab[2][400][4];  // parity: s1(t) | s2(t-1)
  __shared__ __align__(4)  uint8_t  k3tab[2][400][4];  // parity: s2(t) | s3(t-1)
  __shared__ __align__(4)  uint8_t  s_lds[3][200][4];
  __shared__ __align__(16) float    mem_lds[3][200][4];
  __shared__ float  w4_lds[12][201];
  __shared__ float2 bbL[3 * ROWS];
  __shared__ float  saL[3 * 200];
  __shared__ float  smx[12][4];

  const int tid = threadIdx.x;
  const int wv  = tid >> 6;
  const int bg  = blockIdx.x;          // batches bg*4 .. bg*4+3

  for (int idx = tid; idx < 600; idx += NTHR) {
    reinterpret_cast<uint32_t*>(&s_lds[0][0][0])[idx] = 0u;
    reinterpret_cast<float4*>(&mem_lds[0][0][0])[idx] = make_float4(0.f, 0.f, 0.f, 0.f);
  }
  for (int idx = tid; idx < 800; idx += NTHR) {        // zero both parities
    reinterpret_cast<uint32_t*>(&k2tab[0][0][0])[idx] = 0u;
    reinterpret_cast<uint32_t*>(&k3tab[0][0][0])[idx] = 0u;
  }
  for (int idx = tid; idx < 200; idx += NTHR)          // s1(-1) = 0
    k1f[0][120 + idx] = make_float4(0.f, 0.f, 0.f, 0.f);
  for (int idx = tid; idx < 12 * 200; idx += NTHR)
    w4_lds[idx / 200][idx % 200] = W4[idx];
  for (int idx = tid; idx < 3 * ROWS; idx += NTHR) bbL[idx] = bbG[idx];
  for (int idx = tid; idx < 3 * 200; idx += NTHR) saL[idx] = saG[idx];
  if (tid < 480) {                                     // x(0) -> k1f[0]
    const int bat = tid / 120, cf = tid - bat * 120;
    const int c = cf / 40, f = cf - c * 40;
    reinterpret_cast<float*>(&k1f[0][cf])[bat] =
        x[(((size_t)(bg * 4 + bat) * 3 + c) * T_STEPS) * 40 + f];
  }

  float d[5][4];
#pragma unroll
  for (int k = 0; k < 5; ++k)
#pragma unroll
    for (int b = 0; b < 4; ++b) d[k][b] = 0.0f;

  // readout constants (waves 11-13: 192 threads)
  float m4_reg = 0.0f, m4_acc = 0.0f, a4 = 0.0f, b4r = 0.0f;
  if (tid >= 704 && tid < 896) {
    const int o = (tid - 704) >> 4;
    a4 = sigmoidf(tm4[o]); b4r = b4[o];
  }
  __syncthreads();

  const int lane = tid & 63;

  for (int u = 0; u <= T_STEPS + 2; ++u) {
    const int cur = u & 1, oth = cur ^ 1;
    const uint8_t* k1b = reinterpret_cast<const uint8_t*>(&k1f[cur][0]);
    const uint8_t* k2b = reinterpret_cast<const uint8_t*>(&k2tab[oth][0][0]);
    const uint8_t* k3b = reinterpret_cast<const uint8_t*>(&k3tab[cur][0][0]);
    const bool runL1 = (u <= T_STEPS - 1);
    const bool runL2 = (u >= 1 && u <= T_STEPS);
    const bool runL3 = (u >= 2 && u <= T_STEPS + 1);
#pragma unroll
    for (int k = 0; k < 5; ++k) {
      const int id = wv + 16 * k;
      if (id >= 75) break;                   // wave-uniform
      const int layer = id / 25;
      const int r = (id - layer * 25) * 64 + lane;
      if (layer == 0) {
        if (runL1)
          slot_compute<NP1, true, true, false, true>(
              tid, r, w2G, c2G, k1b, bbL, saL, d[k], s_lds[0], mem_lds[0],
              k2tab[cur], k2tab[cur], k1f[oth]);
      } else if (layer == 1) {
        if (runL2)
          slot_compute<NP23, false, true, true, false>(
              tid, r, w2G + PO2, c2G + PO2, k2b, bbL + ROWS, saL + 200,
              d[k], s_lds[1], mem_lds[1], k3tab[oth], k2tab[cur] + 200, nullptr);
      } else {
        if (runL3)
          slot_compute<NP23, false, false, true, false>(
              tid, r, w2G + PO3, c2G + PO3, k3b, bbL + 2 * ROWS, saL + 400,
              d[k], s_lds[2], mem_lds[2], nullptr, k3tab[oth] + 200, nullptr);
      }
    }
    // ---- light-wave duties ---------------------------------------------
    if (wv >= 14) {
      // x-stage for t = u+1
      if (u + 1 <= T_STEPS - 1) {
        const int rid = tid - 896;
        for (int e = rid; e < 480; e += 128) {
          const int bat = e / 120, cf = e - bat * 120;
          const int c = cf / 40, f = cf - c * 40;
          reinterpret_cast<float*>(&k1f[oth][cf])[bat] =
              x[(((size_t)(bg * 4 + bat) * 3 + c) * T_STEPS + (u + 1)) * 40 + f];
        }
      }
    } else if (wv >= 11) {
      // readout for t_r = u-3 (s3(t_r) lives in k3tab[cur][200..])
      if (u >= 3) {
        const int rid = tid - 704;
        const int sub = rid & 3, bat = (rid >> 2) & 3, o = rid >> 4;
        float part = 0.0f;
#pragma unroll 10
        for (int m = 0; m < 50; ++m) {
          const int n = 4 * m + sub;
          part = fmaf(w4_lds[o][n], (float)k3tab[cur][200 + n][bat], part);
        }
        part += __shfl_xor(part, 1);
        part += __shfl_xor(part, 2);
        const float dot = b4r + part;
        m4_reg = a4 * m4_reg + (1.0f - a4) * dot;
        m4_acc += m4_reg;
      }
    }
    __syncthreads();
  }

  // ---- epilogue: log_softmax(acc / T) ----------------------------------
  if (tid >= 704 && tid < 896 && ((tid - 704) & 3) == 0) {
    const int rid = tid - 704;
    smx[rid >> 4][(rid >> 2) & 3] = m4_acc * (1.0f / (float)T_STEPS);
  }
  __syncthreads();
  if (tid < 4) {
    const int bat = tid;
    float v[12], mx = -1e30f;
#pragma unroll
    for (int o = 0; o < 12; ++o) { v[o] = smx[o][bat]; mx = fmaxf(mx, v[o]); }
    float s = 0.0f;
#pragma unroll
    for (int o = 0; o < 12; ++o) s += expf(v[o] - mx);
    const float ls = logf(s);
#pragma unroll
    for (int o = 0; o < 12; ++o)
      out[((size_t)(bg * 4 + bat)) * 12 + o] = v[o] - mx - ls;
  }
}

// ---------------------------------------------------------------------------
extern "C" void kernel_launch(void* const* d_in, const int* in_sizes, int n_in,
                              void* d_out, int out_size, void* d_ws, size_t ws_size,
                              hipStream_t stream) {
  (void)in_sizes; (void)n_in; (void)out_size; (void)ws_size;
  const float* x   = (const float*)d_in[0];
  const float* W1  = (const float*)d_in[1];
  const float* b1  = (const float*)d_in[2];
  const float* tm1 = (const float*)d_in[3];
  const float* tn1 = (const float*)d_in[4];
  const float* W2  = (const float*)d_in[5];
  const float* b2  = (const float*)d_in[6];
  const float* tm2 = (const float*)d_in[7];
  const float* tn2 = (const float*)d_in[8];
  const float* W3  = (const float*)d_in[9];
  const float* b3  = (const float*)d_in[10];
  const float* tm3 = (const float*)d_in[11];
  const float* tn3 = (const float*)d_in[12];
  const float* W4  = (const float*)d_in[13];
  const float* b4  = (const float*)d_in[14];
  const float* tm4 = (const float*)d_in[15];

  uint8_t* ws = (uint8_t*)d_ws;
  const float2*   w2G = (const float2*)(ws + W2_OFF);
  const uint32_t* c2G = (const uint32_t*)(ws + C2_OFF);
  const float2*   bbG = (const float2*)(ws + BB_OFF);
  const float*    saG = (const float*)(ws + SA_OFF);

  prep_kernel<<<dim3(19), dim3(256), 0, stream>>>(
      W1, W2, W3, b1, tn1, tm1, b2, tn2, tm2, b3, tn3, tm3, ws);
  snn_main<<<dim3(NBLK), dim3(NTHR), 0, stream>>>(
      x, W4, b4, tm4, w2G, c2G, bbG, saG, (float*)d_out);
}